// Round 1
// baseline (1754.073 us; speedup 1.0000x reference)
//
#include <hip/hip_runtime.h>
#include <hip/hip_bf16.h>
#include <stdint.h>

// FT-Transformer forward, MI355X gfx950.
// Sizes (fixed): B=128, S=129 (1 CLS + 100 cont + 28 cat), EMB=512, HEADS=8, HD=64,
// DEPTH=6, HID=682 (ReGLU: W0 -> 1364 cols), M = B*S = 16512 = 129*128.
// Strategy: bf16 MFMA (16x16x32) GEMMs with B stored transposed [N,K]; fp32 residual
// stream h; fused MFMA attention per (batch,head).

typedef __hip_bfloat16 bf16_t;
typedef __attribute__((ext_vector_type(8))) __bf16 bf16x8;
typedef __attribute__((ext_vector_type(4))) float floatx4;

#define AS1 __attribute__((address_space(1)))
#define AS3 __attribute__((address_space(3)))

constexpr int M_ROWS = 16512;          // 128 * 129
constexpr float SQRT_EMB_F = 22.627416997969522f;  // sqrt(512): scores DIVIDED by emb**-0.5

__device__ __forceinline__ void gload_lds16(const void* g, void* l) {
  // async global->LDS, 16B per lane; LDS dest must be wave-uniform base + lane*16
  __builtin_amdgcn_global_load_lds((const AS1 unsigned int*)g, (AS3 unsigned int*)l, 16, 0, 0);
}

__device__ __forceinline__ floatx4 mfma16(bf16x8 a, bf16x8 b, floatx4 c) {
  return __builtin_amdgcn_mfma_f32_16x16x32_bf16(a, b, c, 0, 0, 0);
}

// ---------------- weight transpose + fp32->bf16 convert ----------------
// W [L][K][N] fp32 row-major -> WT [L][NP][KP] bf16 row-major, zero-padded.
__global__ __launch_bounds__(256) void transpose_cvt(const float* __restrict__ W,
    bf16_t* __restrict__ WT, int K, int N, int KP, int NP)
{
  __shared__ float tile[32][33];
  int k0 = blockIdx.x * 32, n0 = blockIdx.y * 32;
  const float* Wl = W + (size_t)blockIdx.z * K * N;
  bf16_t* WTl = WT + (size_t)blockIdx.z * NP * KP;
  #pragma unroll
  for (int r = 0; r < 32; r += 8) {
    int k = k0 + threadIdx.y + r, n = n0 + threadIdx.x;
    tile[threadIdx.y + r][threadIdx.x] = (k < K && n < N) ? Wl[(size_t)k * N + n] : 0.f;
  }
  __syncthreads();
  #pragma unroll
  for (int r = 0; r < 32; r += 8) {
    int n = n0 + threadIdx.y + r, k = k0 + threadIdx.x;
    if (n < NP && k < KP)
      WTl[(size_t)n * KP + k] = __float2bfloat16(tile[threadIdx.x][threadIdx.y + r]);
  }
}

// ---------------- feature tokenizer ----------------
// h[b, t, e]: t=0 CLS = tok_w[0]; t in 1..100 cont: tok_w[t]*x[b,28+t-1]+tok_b[t-1];
// t in 101..128 cat j=t-101: cat_emb[int(x[b,j]) + 100*j] + tok_b[t-1].
__global__ __launch_bounds__(256) void tokenizer_kernel(const float* __restrict__ x,
    const float* __restrict__ tok_w, const float* __restrict__ tok_b,
    const float* __restrict__ cat_emb, float* __restrict__ h)
{
  int row = blockIdx.x;           // 0..16511
  int b = row / 129, t = row - b * 129;
  float* hr = h + (size_t)row * 512;
  for (int e = threadIdx.x; e < 512; e += 256) {
    float val;
    if (t == 0) {
      val = tok_w[e];
    } else if (t <= 100) {
      val = tok_w[(size_t)t * 512 + e] * x[(size_t)b * 128 + 28 + (t - 1)]
            + tok_b[(size_t)(t - 1) * 512 + e];
    } else {
      int j = t - 101;
      int idx = (int)x[(size_t)b * 128 + j] + 100 * j;
      val = cat_emb[(size_t)idx * 512 + e] + tok_b[(size_t)(t - 1) * 512 + e];
    }
    hr[e] = val;
  }
}

// ---------------- layernorm (or passthrough) -> bf16 ----------------
__global__ __launch_bounds__(256) void ln_kernel(const float* __restrict__ hin,
    bf16_t* __restrict__ out, const float* __restrict__ g, const float* __restrict__ bta,
    int do_ln)
{
  int row = blockIdx.x, tid = threadIdx.x;
  const float* hr = hin + (size_t)row * 512;
  bf16_t* orow = out + (size_t)row * 512;
  float x0 = hr[tid], x1 = hr[tid + 256];
  if (!do_ln) {
    orow[tid] = __float2bfloat16(x0);
    orow[tid + 256] = __float2bfloat16(x1);
    return;
  }
  float s = x0 + x1, q = x0 * x0 + x1 * x1;
  #pragma unroll
  for (int o = 32; o > 0; o >>= 1) { s += __shfl_down(s, o); q += __shfl_down(q, o); }
  __shared__ float red[8];
  int lane = tid & 63, wid = tid >> 6;
  if (lane == 0) { red[wid] = s; red[wid + 4] = q; }
  __syncthreads();
  s = red[0] + red[1] + red[2] + red[3];
  q = red[4] + red[5] + red[6] + red[7];
  float mean = s * (1.f / 512.f);
  float var = q * (1.f / 512.f) - mean * mean;
  float rstd = rsqrtf(var + 1e-5f);
  orow[tid]       = __float2bfloat16((x0 - mean) * rstd * g[tid] + bta[tid]);
  orow[tid + 256] = __float2bfloat16((x1 - mean) * rstd * g[tid + 256] + bta[tid + 256]);
}

// ---------------- GEMM: C[M,N] = A[M,K](bf16) * BT[N,K](bf16)^T + bias ----------------
// 128x128 tile, BK=32, 4 waves each computing 64x64 (4x4 MFMA tiles).
// RESID: out fp32 = resid + acc + bias (N must equal resid ld = 512).
template <bool RESID, bool OUTBF16>
__global__ __launch_bounds__(256) void gemm_bt(const bf16_t* __restrict__ A,
    const bf16_t* __restrict__ BT, const float* __restrict__ bias, int biasN,
    const float* __restrict__ resid, void* __restrict__ outp, int K, int N)
{
  __shared__ bf16_t As[128 * 32];
  __shared__ bf16_t Bs[128 * 32];
  const int m0 = blockIdx.y * 128, n0 = blockIdx.x * 128;
  const int tid = threadIdx.x;
  const int w = tid >> 6, l = tid & 63, l15 = l & 15, quad = l >> 4;
  const int wm = (w >> 1) * 64, wn = (w & 1) * 64;
  const bf16_t* Ab = A + (size_t)m0 * K;
  const bf16_t* Bb = BT + (size_t)n0 * K;
  const int r0 = tid >> 2, kc0 = (tid & 3) * 8;  // 4 x 16B chunks per 32-elem row

  floatx4 z4 = {0.f, 0.f, 0.f, 0.f};
  floatx4 acc[4][4];
  #pragma unroll
  for (int i = 0; i < 4; i++)
    #pragma unroll
    for (int j = 0; j < 4; j++) acc[i][j] = z4;

  for (int kk = 0; kk < K; kk += 32) {
    gload_lds16(Ab + (size_t)r0 * K + kk + kc0,        &As[tid * 8]);
    gload_lds16(Ab + (size_t)(r0 + 64) * K + kk + kc0, &As[(tid + 256) * 8]);
    gload_lds16(Bb + (size_t)r0 * K + kk + kc0,        &Bs[tid * 8]);
    gload_lds16(Bb + (size_t)(r0 + 64) * K + kk + kc0, &Bs[(tid + 256) * 8]);
    __syncthreads();
    bf16x8 af[4], bfr[4];
    #pragma unroll
    for (int i = 0; i < 4; i++) {
      af[i]  = *(const bf16x8*)&As[(wm + i * 16 + l15) * 32 + quad * 8];
      bfr[i] = *(const bf16x8*)&Bs[(wn + i * 16 + l15) * 32 + quad * 8];
    }
    #pragma unroll
    for (int i = 0; i < 4; i++)
      #pragma unroll
      for (int j = 0; j < 4; j++)
        acc[i][j] = mfma16(af[i], bfr[j], acc[i][j]);
    __syncthreads();
  }

  #pragma unroll
  for (int j = 0; j < 4; j++) {
    int col = n0 + wn + j * 16 + l15;
    float bv = (col < biasN) ? bias[col] : 0.f;
    #pragma unroll
    for (int i = 0; i < 4; i++) {
      int row_b = m0 + wm + i * 16 + quad * 4;
      #pragma unroll
      for (int r = 0; r < 4; r++) {
        size_t idx = (size_t)(row_b + r) * N + col;
        float v = acc[i][j][r] + bv;
        if (RESID) v += resid[idx];
        if (OUTBF16) ((bf16_t*)outp)[idx] = __float2bfloat16(v);
        else         ((float*)outp)[idx] = v;
      }
    }
  }
}

// ---------------- fused attention: one block per (batch, head) ----------------
// qkv [M,1536] bf16; head hh: q at col hh*192, k at +64, v at +128.
// scores = (q.k) * sqrt(512); attn = softmax(softmax(scores)); o = attn @ v -> attnout [M,512].
constexpr int SP = 160;  // S=129 padded to 5*32
__global__ __launch_bounds__(256) void attn_kernel(const bf16_t* __restrict__ qkv,
                                                   bf16_t* __restrict__ attnout)
{
  __shared__ bf16_t k_lds[SP * 64];    // [s_kv][d]
  __shared__ bf16_t vt_lds[64 * SP];   // [d][s_kv]
  __shared__ float sc[32 * SP];        // scores for one 32-row q tile; p (bf16) overlays
  bf16_t* p_lds = (bf16_t*)sc;

  const int bh = blockIdx.x, b = bh >> 3, hh = bh & 7;
  const int tid = threadIdx.x;
  const int w = tid >> 6, l = tid & 63, l15 = l & 15, quad = l >> 4;
  const bf16_t* base = qkv + (size_t)b * 129 * 1536 + hh * 192;

  // zero LDS (covers the s>=129 pad rows), then load K and V^T
  for (int i = tid; i < SP * 64 / 2; i += 256) {
    ((unsigned int*)k_lds)[i] = 0u;
    ((unsigned int*)vt_lds)[i] = 0u;
  }
  __syncthreads();
  for (int c = tid; c < 129 * 8; c += 256) {
    int s = c >> 3, ch = c & 7;
    *(float4*)&k_lds[s * 64 + ch * 8] = *(const float4*)(base + (size_t)s * 1536 + 64 + ch * 8);
  }
  for (int c = tid; c < 129 * 8; c += 256) {
    int s = c >> 3, ch = c & 7;
    float4 tmp4 = *(const float4*)(base + (size_t)s * 1536 + 128 + ch * 8);
    const bf16_t* tv = (const bf16_t*)&tmp4;
    #pragma unroll
    for (int j = 0; j < 8; j++) vt_lds[(size_t)(ch * 8 + j) * SP + s] = tv[j];
  }
  __syncthreads();

  for (int qt = 0; qt < 5; qt++) {
    // ---- QK^T for 32 q rows (2 m-tiles), n-tiles split across waves ----
    bf16x8 zq = {};
    bf16x8 aq[2][2];
    #pragma unroll
    for (int mt = 0; mt < 2; mt++) {
      int m = qt * 32 + mt * 16 + l15;
      #pragma unroll
      for (int t = 0; t < 2; t++) {
        aq[mt][t] = (m < 129) ? *(const bf16x8*)(base + (size_t)m * 1536 + t * 32 + quad * 8)
                              : zq;
      }
    }
    for (int nt = w; nt < 10; nt += 4) {
      floatx4 a0 = {0.f, 0.f, 0.f, 0.f}, a1 = {0.f, 0.f, 0.f, 0.f};
      #pragma unroll
      for (int t = 0; t < 2; t++) {
        bf16x8 kf = *(const bf16x8*)&k_lds[(nt * 16 + l15) * 64 + t * 32 + quad * 8];
        a0 = mfma16(aq[0][t], kf, a0);
        a1 = mfma16(aq[1][t], kf, a1);
      }
      #pragma unroll
      for (int r = 0; r < 4; r++) {
        sc[(quad * 4 + r) * SP + nt * 16 + l15]        = a0[r] * SQRT_EMB_F;
        sc[(16 + quad * 4 + r) * SP + nt * 16 + l15]   = a1[r] * SQRT_EMB_F;
      }
    }
    __syncthreads();

    // ---- double softmax, 8 threads per row, all in registers ----
    {
      int row = tid >> 3, sub = tid & 7;
      float vv[20];
      float mx = -1e30f;
      #pragma unroll
      for (int c = 0; c < 20; c++) {
        int j = sub + c * 8;
        vv[c] = (j < 129) ? sc[row * SP + j] : -1e30f;
        mx = fmaxf(mx, vv[c]);
      }
      #pragma unroll
      for (int o = 1; o < 8; o <<= 1) mx = fmaxf(mx, __shfl_xor(mx, o, 8));
      float sum = 0.f;
      #pragma unroll
      for (int c = 0; c < 20; c++) {
        int j = sub + c * 8;
        vv[c] = (j < 129) ? __expf(vv[c] - mx) : 0.f;
        sum += vv[c];
      }
      #pragma unroll
      for (int o = 1; o < 8; o <<= 1) sum += __shfl_xor(sum, o, 8);
      float inv = 1.f / sum;
      float mx2 = 0.f;
      #pragma unroll
      for (int c = 0; c < 20; c++) { vv[c] *= inv; mx2 = fmaxf(mx2, vv[c]); }
      #pragma unroll
      for (int o = 1; o < 8; o <<= 1) mx2 = fmaxf(mx2, __shfl_xor(mx2, o, 8));
      float sum2 = 0.f;
      #pragma unroll
      for (int c = 0; c < 20; c++) {
        int j = sub + c * 8;
        vv[c] = (j < 129) ? __expf(vv[c] - mx2) : 0.f;
        sum2 += vv[c];
      }
      #pragma unroll
      for (int o = 1; o < 8; o <<= 1) sum2 += __shfl_xor(sum2, o, 8);
      float inv2 = 1.f / sum2;
      __syncthreads();  // everyone done reading sc before bf16 overlay write
      #pragma unroll
      for (int c = 0; c < 20; c++) {
        int j = sub + c * 8;
        p_lds[row * SP + j] = __float2bfloat16(vv[c] * inv2);  // pads -> 0
      }
    }
    __syncthreads();

    // ---- PV: o[32,64] = p[32,160] @ v[160,64]; wave -> (mt, 2 d-tiles) ----
    {
      int mt = w >> 1, nt0 = (w & 1) * 2;
      floatx4 oacc[2];
      oacc[0] = floatx4{0.f, 0.f, 0.f, 0.f};
      oacc[1] = floatx4{0.f, 0.f, 0.f, 0.f};
      #pragma unroll
      for (int t = 0; t < 5; t++) {
        bf16x8 pf = *(const bf16x8*)&p_lds[(mt * 16 + l15) * SP + t * 32 + quad * 8];
        #pragma unroll
        for (int n = 0; n < 2; n++) {
          bf16x8 vf = *(const bf16x8*)&vt_lds[((nt0 + n) * 16 + l15) * SP + t * 32 + quad * 8];
          oacc[n] = mfma16(pf, vf, oacc[n]);
        }
      }
      #pragma unroll
      for (int n = 0; n < 2; n++)
        #pragma unroll
        for (int r = 0; r < 4; r++) {
          int sq = qt * 32 + mt * 16 + quad * 4 + r;
          if (sq < 129)
            attnout[((size_t)b * 129 + sq) * 512 + hh * 64 + (nt0 + n) * 16 + l15] =
                __float2bfloat16(oacc[n][r]);
        }
    }
    __syncthreads();  // protect sc/p reuse next q-tile
  }
}

// ---------------- ReGLU: y[M,1408] -> o[M,704] (cols>=682 zero-padded) ----------------
__global__ __launch_bounds__(256) void reglu_kernel(const bf16_t* __restrict__ y,
                                                    bf16_t* __restrict__ o)
{
  int m = blockIdx.x;
  const bf16_t* yr = y + (size_t)m * 1408;
  bf16_t* orow = o + (size_t)m * 704;
  for (int j = threadIdx.x; j < 704; j += 256) {
    float val = 0.f;
    if (j < 682) {
      float a = __bfloat162float(yr[j]);
      float bb = __bfloat162float(yr[682 + j]);
      val = a * fmaxf(bb, 0.f);
    }
    orow[j] = __float2bfloat16(val);
  }
}

// ---------------- output: CLS rows ----------------
__global__ __launch_bounds__(256) void out_copy(const float* __restrict__ h,
                                                float* __restrict__ out)
{
  int b = blockIdx.x, e = threadIdx.x;
  out[(size_t)b * 512 + e]       = h[(size_t)b * 129 * 512 + e];
  out[(size_t)b * 512 + e + 256] = h[(size_t)b * 129 * 512 + e + 256];
}

// ---------------- host launcher ----------------
extern "C" void kernel_launch(void* const* d_in, const int* in_sizes, int n_in,
                              void* d_out, int out_size, void* d_ws, size_t ws_size,
                              hipStream_t stream)
{
  const float* x       = (const float*)d_in[0];
  const float* tok_w   = (const float*)d_in[1];
  const float* tok_b   = (const float*)d_in[2];
  const float* cat_emb = (const float*)d_in[3];
  const float* Wqkv    = (const float*)d_in[4];
  const float* bqkv    = (const float*)d_in[5];
  const float* Wout    = (const float*)d_in[6];
  const float* bout    = (const float*)d_in[7];
  const float* W0      = (const float*)d_in[8];
  const float* b0      = (const float*)d_in[9];
  const float* W1      = (const float*)d_in[10];
  const float* b1      = (const float*)d_in[11];
  const float* ln0_g   = (const float*)d_in[12];
  const float* ln0_b   = (const float*)d_in[13];
  const float* ln1_g   = (const float*)d_in[14];
  const float* ln1_b   = (const float*)d_in[15];

  // workspace carve-up (~167 MB total)
  size_t off = 0;
  char* base = (char*)d_ws;
  auto alloc = [&](size_t n) { char* p = base + off; off += (n + 255) & ~(size_t)255; return p; };
  float*  h     = (float*) alloc((size_t)M_ROWS * 512 * 4);
  bf16_t* ab    = (bf16_t*)alloc((size_t)M_ROWS * 512 * 2);   // LN outputs (GEMM A)
  bf16_t* qkv   = (bf16_t*)alloc((size_t)M_ROWS * 1536 * 2);  // also reused as ffn1 [M,1408]
  bf16_t* attno = (bf16_t*)alloc((size_t)M_ROWS * 512 * 2);
  bf16_t* regl  = (bf16_t*)alloc((size_t)M_ROWS * 704 * 2);
  bf16_t* WqkvT = (bf16_t*)alloc((size_t)6 * 1536 * 512 * 2);
  bf16_t* WoutT = (bf16_t*)alloc((size_t)6 * 512 * 512 * 2);
  bf16_t* W0T   = (bf16_t*)alloc((size_t)6 * 1408 * 512 * 2);
  bf16_t* W1T   = (bf16_t*)alloc((size_t)6 * 512 * 704 * 2);
  bf16_t* ffn1  = qkv;
  (void)ws_size; (void)in_sizes; (void)n_in; (void)out_size;

  dim3 tb(32, 8, 1);
  transpose_cvt<<<dim3(16, 48, 6), tb, 0, stream>>>(Wqkv, WqkvT, 512, 1536, 512, 1536);
  transpose_cvt<<<dim3(16, 16, 6), tb, 0, stream>>>(Wout, WoutT, 512, 512, 512, 512);
  transpose_cvt<<<dim3(16, 44, 6), tb, 0, stream>>>(W0, W0T, 512, 1364, 512, 1408);
  transpose_cvt<<<dim3(22, 16, 6), tb, 0, stream>>>(W1, W1T, 682, 512, 704, 512);

  tokenizer_kernel<<<M_ROWS, 256, 0, stream>>>(x, tok_w, tok_b, cat_emb, h);

  for (int i = 0; i < 6; i++) {
    ln_kernel<<<M_ROWS, 256, 0, stream>>>(h, ab, ln0_g + (size_t)i * 512, ln0_b + (size_t)i * 512,
                                          i > 0 ? 1 : 0);
    gemm_bt<false, true><<<dim3(12, 129), 256, 0, stream>>>(
        ab, WqkvT + (size_t)i * 1536 * 512, bqkv + (size_t)i * 1536, 1536, nullptr, qkv, 512, 1536);
    attn_kernel<<<1024, 256, 0, stream>>>(qkv, attno);
    gemm_bt<true, false><<<dim3(4, 129), 256, 0, stream>>>(
        attno, WoutT + (size_t)i * 512 * 512, bout + (size_t)i * 512, 512, h, h, 512, 512);
    ln_kernel<<<M_ROWS, 256, 0, stream>>>(h, ab, ln1_g + (size_t)i * 512, ln1_b + (size_t)i * 512, 1);
    gemm_bt<false, true><<<dim3(11, 129), 256, 0, stream>>>(
        ab, W0T + (size_t)i * 1408 * 512, b0 + (size_t)i * 1364, 1364, nullptr, ffn1, 512, 1408);
    reglu_kernel<<<M_ROWS, 256, 0, stream>>>(ffn1, regl);
    gemm_bt<true, false><<<dim3(4, 129), 256, 0, stream>>>(
        regl, W1T + (size_t)i * 512 * 704, b1 + (size_t)i * 512, 512, h, h, 704, 512);
  }

  out_copy<<<128, 256, 0, stream>>>(h, (float*)d_out);
}

// Round 2
// 1508.540 us; speedup vs baseline: 1.1628x; 1.1628x over previous
//
#include <hip/hip_runtime.h>
#include <hip/hip_bf16.h>
#include <stdint.h>

// FT-Transformer forward, MI355X gfx950. Round 2:
//  - XOR-swizzled LDS k-chunks in GEMM (8-way -> 2-way bank conflicts)
//  - XCD-aware block remap (contiguous m-range per XCD for L2 A-reuse)
//  - ReGLU fused into W0 GEMM epilogue (pair-interleaved W0^T columns + shfl_xor)
//  - wave-per-row LN (no LDS/syncthreads), tokenizer emits bf16 directly
//  - attention reads K from global (L2) instead of LDS: 60->40KB LDS, 4 blocks/CU

typedef __hip_bfloat16 bf16_t;
typedef __attribute__((ext_vector_type(8))) __bf16 bf16x8;
typedef __attribute__((ext_vector_type(4))) float floatx4;

#define AS1 __attribute__((address_space(1)))
#define AS3 __attribute__((address_space(3)))

constexpr int M_ROWS = 16512;          // 128 * 129
constexpr float SQRT_EMB_F = 22.627416997969522f;  // scores DIVIDED by emb**-0.5

__device__ __forceinline__ void gload_lds16(const void* g, void* l) {
  __builtin_amdgcn_global_load_lds((const AS1 unsigned int*)g, (AS3 unsigned int*)l, 16, 0, 0);
}

__device__ __forceinline__ floatx4 mfma16(bf16x8 a, bf16x8 b, floatx4 c) {
  return __builtin_amdgcn_mfma_f32_16x16x32_bf16(a, b, c, 0, 0, 0);
}

// ---------------- weight transpose + fp32->bf16 convert ----------------
// W [L][K][N] fp32 -> WT [L][NP][KP] bf16, zero-padded.
// PERM=1: output col n maps to source col (n&1) ? 682+(n>>1) : (n>>1)  (ReGLU pairing)
template <int PERM>
__global__ __launch_bounds__(256) void transpose_cvt(const float* __restrict__ W,
    bf16_t* __restrict__ WT, int K, int N, int KP, int NP)
{
  __shared__ float tile[32][33];
  int k0 = blockIdx.x * 32, n0 = blockIdx.y * 32;
  const float* Wl = W + (size_t)blockIdx.z * K * N;
  bf16_t* WTl = WT + (size_t)blockIdx.z * NP * KP;
  #pragma unroll
  for (int r = 0; r < 32; r += 8) {
    int k = k0 + threadIdx.y + r, n = n0 + threadIdx.x;
    int srcn = PERM ? ((n & 1) ? 682 + (n >> 1) : (n >> 1)) : n;
    int valid = (k < K) && (PERM ? (n < 1364) : (n < N));
    tile[threadIdx.y + r][threadIdx.x] = valid ? Wl[(size_t)k * N + srcn] : 0.f;
  }
  __syncthreads();
  #pragma unroll
  for (int r = 0; r < 32; r += 8) {
    int n = n0 + threadIdx.y + r, k = k0 + threadIdx.x;
    if (n < NP && k < KP)
      WTl[(size_t)n * KP + k] = __float2bfloat16(tile[threadIdx.x][threadIdx.y + r]);
  }
}

// ---------------- feature tokenizer (writes fp32 h AND bf16 ab for layer 0) ----------------
__global__ __launch_bounds__(256) void tokenizer_kernel(const float* __restrict__ x,
    const float* __restrict__ tok_w, const float* __restrict__ tok_b,
    const float* __restrict__ cat_emb, float* __restrict__ h, bf16_t* __restrict__ ab)
{
  int row = blockIdx.x;           // 0..16511
  int b = row / 129, t = row - b * 129;
  float* hr = h + (size_t)row * 512;
  bf16_t* ar = ab + (size_t)row * 512;
  for (int e = threadIdx.x; e < 512; e += 256) {
    float val;
    if (t == 0) {
      val = tok_w[e];
    } else if (t <= 100) {
      val = tok_w[(size_t)t * 512 + e] * x[(size_t)b * 128 + 28 + (t - 1)]
            + tok_b[(size_t)(t - 1) * 512 + e];
    } else {
      int j = t - 101;
      int idx = (int)x[(size_t)b * 128 + j] + 100 * j;
      val = cat_emb[(size_t)idx * 512 + e] + tok_b[(size_t)(t - 1) * 512 + e];
    }
    hr[e] = val;
    ar[e] = __float2bfloat16(val);
  }
}

// ---------------- layernorm: one 64-lane wave per row, no LDS ----------------
__global__ __launch_bounds__(256) void ln_kernel(const float* __restrict__ hin,
    bf16_t* __restrict__ out, const float* __restrict__ g, const float* __restrict__ bta)
{
  int row = blockIdx.x * 4 + (threadIdx.x >> 6);
  int lane = threadIdx.x & 63;
  const float* hr = hin + (size_t)row * 512 + lane * 8;
  float4 v0 = *(const float4*)hr;
  float4 v1 = *(const float4*)(hr + 4);
  float s = v0.x + v0.y + v0.z + v0.w + v1.x + v1.y + v1.z + v1.w;
  float q = v0.x * v0.x + v0.y * v0.y + v0.z * v0.z + v0.w * v0.w
          + v1.x * v1.x + v1.y * v1.y + v1.z * v1.z + v1.w * v1.w;
  #pragma unroll
  for (int o = 1; o < 64; o <<= 1) { s += __shfl_xor(s, o); q += __shfl_xor(q, o); }
  float mean = s * (1.f / 512.f);
  float var = q * (1.f / 512.f) - mean * mean;
  float rstd = rsqrtf(var + 1e-5f);
  float4 g0 = *(const float4*)(g + lane * 8);
  float4 g1 = *(const float4*)(g + lane * 8 + 4);
  float4 b0v = *(const float4*)(bta + lane * 8);
  float4 b1v = *(const float4*)(bta + lane * 8 + 4);
  bf16x8 o8;
  o8[0] = (__bf16)__float2bfloat16((v0.x - mean) * rstd * g0.x + b0v.x);
  o8[1] = (__bf16)__float2bfloat16((v0.y - mean) * rstd * g0.y + b0v.y);
  o8[2] = (__bf16)__float2bfloat16((v0.z - mean) * rstd * g0.z + b0v.z);
  o8[3] = (__bf16)__float2bfloat16((v0.w - mean) * rstd * g0.w + b0v.w);
  o8[4] = (__bf16)__float2bfloat16((v1.x - mean) * rstd * g1.x + b1v.x);
  o8[5] = (__bf16)__float2bfloat16((v1.y - mean) * rstd * g1.y + b1v.y);
  o8[6] = (__bf16)__float2bfloat16((v1.z - mean) * rstd * g1.z + b1v.z);
  o8[7] = (__bf16)__float2bfloat16((v1.w - mean) * rstd * g1.w + b1v.w);
  *(bf16x8*)(out + (size_t)row * 512 + lane * 8) = o8;
}

// ---------------- GEMM: C[M,N] = A[M,K](bf16) * BT[N,K]^T + bias ----------------
// MODE 0: bf16 out.  MODE 1: fp32 out = resid + acc + bias.
// MODE 2: ReGLU out bf16 [M, N/2]: paired cols (a=even, b=odd), out = a*relu(b),
//         bias index permuted (col&1 ? 682+(col>>1) : col>>1), biasN applies to permuted space.
template <int MODE>
__global__ __launch_bounds__(256) void gemm_bt(const bf16_t* __restrict__ A,
    const bf16_t* __restrict__ BT, const float* __restrict__ bias, int biasN,
    const float* __restrict__ resid, void* __restrict__ outp, int K, int N)
{
  __shared__ bf16_t As[128 * 32];
  __shared__ bf16_t Bs[128 * 32];
  // XCD-aware remap: blocks with lin%8==x get a contiguous idx chunk -> contiguous m range
  const int total = gridDim.x * gridDim.y;
  const int lin = blockIdx.y * gridDim.x + blockIdx.x;
  const int xcd = lin & 7, kb = lin >> 3;
  const int qch = total >> 3, rch = total & 7;
  const int idx = xcd * qch + (xcd < rch ? xcd : rch) + kb;
  const int bm = idx / gridDim.x;
  const int bn = idx - bm * gridDim.x;
  const int m0 = bm * 128, n0 = bn * 128;

  const int tid = threadIdx.x;
  const int w = tid >> 6, l = tid & 63, l15 = l & 15, quad = l >> 4;
  const int wm = (w >> 1) * 64, wn = (w & 1) * 64;
  const bf16_t* Ab = A + (size_t)m0 * K;
  const bf16_t* Bb = BT + (size_t)n0 * K;
  const int r0 = tid >> 2;
  const int kc0 = (((tid & 3) ^ ((tid >> 3) & 3))) * 8;  // XOR-swizzled chunk
  const int swz = (l15 >> 1) & 3;                        // read-side swizzle

  floatx4 z4 = {0.f, 0.f, 0.f, 0.f};
  floatx4 acc[4][4];
  #pragma unroll
  for (int i = 0; i < 4; i++)
    #pragma unroll
    for (int j = 0; j < 4; j++) acc[i][j] = z4;

  for (int kk = 0; kk < K; kk += 32) {
    gload_lds16(Ab + (size_t)r0 * K + kk + kc0,        &As[tid * 8]);
    gload_lds16(Ab + (size_t)(r0 + 64) * K + kk + kc0, &As[(tid + 256) * 8]);
    gload_lds16(Bb + (size_t)r0 * K + kk + kc0,        &Bs[tid * 8]);
    gload_lds16(Bb + (size_t)(r0 + 64) * K + kk + kc0, &Bs[(tid + 256) * 8]);
    __syncthreads();
    bf16x8 af[4], bfr[4];
    #pragma unroll
    for (int i = 0; i < 4; i++) {
      af[i]  = *(const bf16x8*)&As[(wm + i * 16 + l15) * 32 + ((quad ^ swz) * 8)];
      bfr[i] = *(const bf16x8*)&Bs[(wn + i * 16 + l15) * 32 + ((quad ^ swz) * 8)];
    }
    #pragma unroll
    for (int i = 0; i < 4; i++)
      #pragma unroll
      for (int j = 0; j < 4; j++)
        acc[i][j] = mfma16(af[i], bfr[j], acc[i][j]);
    __syncthreads();
  }

  #pragma unroll
  for (int j = 0; j < 4; j++) {
    int col = n0 + wn + j * 16 + l15;
    float bv = 0.f;
    if (MODE == 2) {
      if (col < biasN) bv = bias[(col & 1) ? 682 + (col >> 1) : (col >> 1)];
    } else {
      if (col < biasN) bv = bias[col];
    }
    #pragma unroll
    for (int i = 0; i < 4; i++) {
      int row_b = m0 + wm + i * 16 + quad * 4;
      #pragma unroll
      for (int r = 0; r < 4; r++) {
        float v = acc[i][j][r] + bv;
        if (MODE == 2) {
          float other = __shfl_xor(v, 1);
          if (!(l15 & 1)) {
            size_t idx2 = (size_t)(row_b + r) * (N >> 1) + (col >> 1);
            ((bf16_t*)outp)[idx2] = __float2bfloat16(v * fmaxf(other, 0.f));
          }
        } else {
          size_t idx2 = (size_t)(row_b + r) * N + col;
          if (MODE == 1) ((float*)outp)[idx2] = v + resid[idx2];
          else           ((bf16_t*)outp)[idx2] = __float2bfloat16(v);
        }
      }
    }
  }
}

// ---------------- fused attention: one block per (batch, head) ----------------
// qkv [M,1536] bf16; head hh: q at col hh*192, k at +64, v at +128.
// K fragments read straight from global (L2); V^T staged in LDS; 40KB LDS total.
constexpr int SP = 160;  // S=129 padded to 5*32
__global__ __launch_bounds__(256) void attn_kernel(const bf16_t* __restrict__ qkv,
                                                   bf16_t* __restrict__ attnout)
{
  __shared__ bf16_t vt_lds[64 * SP];   // [d][s_kv]
  __shared__ float sc[32 * SP];        // scores for one 32-row q tile; p (bf16) overlays
  bf16_t* p_lds = (bf16_t*)sc;

  const int bh = blockIdx.x, b = bh >> 3, hh = bh & 7;
  const int tid = threadIdx.x;
  const int w = tid >> 6, l = tid & 63, l15 = l & 15, quad = l >> 4;
  const bf16_t* base = qkv + (size_t)b * 129 * 1536 + hh * 192;

  for (int i = tid; i < SP * 64 / 2; i += 256) ((unsigned int*)vt_lds)[i] = 0u;
  __syncthreads();
  for (int c = tid; c < 129 * 8; c += 256) {
    int s = c >> 3, ch = c & 7;
    float4 tmp4 = *(const float4*)(base + (size_t)s * 1536 + 128 + ch * 8);
    const bf16_t* tv = (const bf16_t*)&tmp4;
    #pragma unroll
    for (int j = 0; j < 8; j++) vt_lds[(size_t)(ch * 8 + j) * SP + s] = tv[j];
  }
  __syncthreads();

  for (int qt = 0; qt < 5; qt++) {
    bf16x8 zq = {};
    bf16x8 aq[2][2];
    #pragma unroll
    for (int mt = 0; mt < 2; mt++) {
      int m = qt * 32 + mt * 16 + l15;
      #pragma unroll
      for (int t = 0; t < 2; t++)
        aq[mt][t] = (m < 129) ? *(const bf16x8*)(base + (size_t)m * 1536 + t * 32 + quad * 8) : zq;
    }
    for (int nt = w; nt < 10; nt += 4) {
      int krow = nt * 16 + l15;
      floatx4 a0 = {0.f, 0.f, 0.f, 0.f}, a1 = {0.f, 0.f, 0.f, 0.f};
      #pragma unroll
      for (int t = 0; t < 2; t++) {
        bf16x8 kf = (krow < 129)
            ? *(const bf16x8*)(base + (size_t)krow * 1536 + 64 + t * 32 + quad * 8) : zq;
        a0 = mfma16(aq[0][t], kf, a0);
        a1 = mfma16(aq[1][t], kf, a1);
      }
      #pragma unroll
      for (int r = 0; r < 4; r++) {
        sc[(quad * 4 + r) * SP + nt * 16 + l15]      = a0[r] * SQRT_EMB_F;
        sc[(16 + quad * 4 + r) * SP + nt * 16 + l15] = a1[r] * SQRT_EMB_F;
      }
    }
    __syncthreads();

    // double softmax, 8 threads per row
    {
      int row = tid >> 3, sub = tid & 7;
      float vv[20];
      float mx = -1e30f;
      #pragma unroll
      for (int c = 0; c < 20; c++) {
        int j = sub + c * 8;
        vv[c] = (j < 129) ? sc[row * SP + j] : -1e30f;
        mx = fmaxf(mx, vv[c]);
      }
      #pragma unroll
      for (int o = 1; o < 8; o <<= 1) mx = fmaxf(mx, __shfl_xor(mx, o, 8));
      float sum = 0.f;
      #pragma unroll
      for (int c = 0; c < 20; c++) {
        int j = sub + c * 8;
        vv[c] = (j < 129) ? __expf(vv[c] - mx) : 0.f;
        sum += vv[c];
      }
      #pragma unroll
      for (int o = 1; o < 8; o <<= 1) sum += __shfl_xor(sum, o, 8);
      float inv = 1.f / sum;
      float mx2 = 0.f;
      #pragma unroll
      for (int c = 0; c < 20; c++) { vv[c] *= inv; mx2 = fmaxf(mx2, vv[c]); }
      #pragma unroll
      for (int o = 1; o < 8; o <<= 1) mx2 = fmaxf(mx2, __shfl_xor(mx2, o, 8));
      float sum2 = 0.f;
      #pragma unroll
      for (int c = 0; c < 20; c++) {
        int j = sub + c * 8;
        vv[c] = (j < 129) ? __expf(vv[c] - mx2) : 0.f;
        sum2 += vv[c];
      }
      #pragma unroll
      for (int o = 1; o < 8; o <<= 1) sum2 += __shfl_xor(sum2, o, 8);
      float inv2 = 1.f / sum2;
      __syncthreads();  // all reads of sc done before bf16 overlay write
      #pragma unroll
      for (int c = 0; c < 20; c++) {
        int j = sub + c * 8;
        p_lds[row * SP + j] = __float2bfloat16(vv[c] * inv2);  // pads -> 0
      }
    }
    __syncthreads();

    // PV: o[32,64] = p[32,160] @ v[160,64]
    {
      int mt = w >> 1, nt0 = (w & 1) * 2;
      floatx4 oacc[2];
      oacc[0] = floatx4{0.f, 0.f, 0.f, 0.f};
      oacc[1] = floatx4{0.f, 0.f, 0.f, 0.f};
      #pragma unroll
      for (int t = 0; t < 5; t++) {
        bf16x8 pf = *(const bf16x8*)&p_lds[(mt * 16 + l15) * SP + t * 32 + quad * 8];
        #pragma unroll
        for (int n = 0; n < 2; n++) {
          bf16x8 vf = *(const bf16x8*)&vt_lds[((nt0 + n) * 16 + l15) * SP + t * 32 + quad * 8];
          oacc[n] = mfma16(pf, vf, oacc[n]);
        }
      }
      #pragma unroll
      for (int n = 0; n < 2; n++)
        #pragma unroll
        for (int r = 0; r < 4; r++) {
          int sq = qt * 32 + mt * 16 + quad * 4 + r;
          if (sq < 129)
            attnout[((size_t)b * 129 + sq) * 512 + hh * 64 + (nt0 + n) * 16 + l15] =
                __float2bfloat16(oacc[n][r]);
        }
    }
    __syncthreads();
  }
}

// ---------------- output: CLS rows ----------------
__global__ __launch_bounds__(256) void out_copy(const float* __restrict__ h,
                                                float* __restrict__ out)
{
  int b = blockIdx.x, e = threadIdx.x;
  out[(size_t)b * 512 + e]       = h[(size_t)b * 129 * 512 + e];
  out[(size_t)b * 512 + e + 256] = h[(size_t)b * 129 * 512 + e + 256];
}

// ---------------- host launcher ----------------
extern "C" void kernel_launch(void* const* d_in, const int* in_sizes, int n_in,
                              void* d_out, int out_size, void* d_ws, size_t ws_size,
                              hipStream_t stream)
{
  const float* x       = (const float*)d_in[0];
  const float* tok_w   = (const float*)d_in[1];
  const float* tok_b   = (const float*)d_in[2];
  const float* cat_emb = (const float*)d_in[3];
  const float* Wqkv    = (const float*)d_in[4];
  const float* bqkv    = (const float*)d_in[5];
  const float* Wout    = (const float*)d_in[6];
  const float* bout    = (const float*)d_in[7];
  const float* W0      = (const float*)d_in[8];
  const float* b0      = (const float*)d_in[9];
  const float* W1      = (const float*)d_in[10];
  const float* b1      = (const float*)d_in[11];
  const float* ln0_g   = (const float*)d_in[12];
  const float* ln0_b   = (const float*)d_in[13];
  const float* ln1_g   = (const float*)d_in[14];
  const float* ln1_b   = (const float*)d_in[15];

  size_t off = 0;
  char* base = (char*)d_ws;
  auto alloc = [&](size_t n) { char* p = base + off; off += (n + 255) & ~(size_t)255; return p; };
  float*  h     = (float*) alloc((size_t)M_ROWS * 512 * 4);
  bf16_t* ab    = (bf16_t*)alloc((size_t)M_ROWS * 512 * 2);   // LN outputs (GEMM A)
  bf16_t* qkv   = (bf16_t*)alloc((size_t)M_ROWS * 1536 * 2);
  bf16_t* attno = (bf16_t*)alloc((size_t)M_ROWS * 512 * 2);
  bf16_t* regl  = (bf16_t*)alloc((size_t)M_ROWS * 704 * 2);
  bf16_t* WqkvT = (bf16_t*)alloc((size_t)6 * 1536 * 512 * 2);
  bf16_t* WoutT = (bf16_t*)alloc((size_t)6 * 512 * 512 * 2);
  bf16_t* W0T   = (bf16_t*)alloc((size_t)6 * 1408 * 512 * 2);  // pair-interleaved
  bf16_t* W1T   = (bf16_t*)alloc((size_t)6 * 512 * 704 * 2);
  (void)ws_size; (void)in_sizes; (void)n_in; (void)out_size;

  dim3 tb(32, 8, 1);
  transpose_cvt<0><<<dim3(16, 48, 6), tb, 0, stream>>>(Wqkv, WqkvT, 512, 1536, 512, 1536);
  transpose_cvt<0><<<dim3(16, 16, 6), tb, 0, stream>>>(Wout, WoutT, 512, 512, 512, 512);
  transpose_cvt<1><<<dim3(16, 44, 6), tb, 0, stream>>>(W0, W0T, 512, 1364, 512, 1408);
  transpose_cvt<0><<<dim3(22, 16, 6), tb, 0, stream>>>(W1, W1T, 682, 512, 704, 512);

  tokenizer_kernel<<<M_ROWS, 256, 0, stream>>>(x, tok_w, tok_b, cat_emb, h, ab);

  for (int i = 0; i < 6; i++) {
    if (i)
      ln_kernel<<<M_ROWS / 4, 256, 0, stream>>>(h, ab, ln0_g + (size_t)i * 512,
                                                ln0_b + (size_t)i * 512);
    gemm_bt<0><<<dim3(12, 129), 256, 0, stream>>>(
        ab, WqkvT + (size_t)i * 1536 * 512, bqkv + (size_t)i * 1536, 1536, nullptr, qkv, 512, 1536);
    attn_kernel<<<1024, 256, 0, stream>>>(qkv, attno);
    gemm_bt<1><<<dim3(4, 129), 256, 0, stream>>>(
        attno, WoutT + (size_t)i * 512 * 512, bout + (size_t)i * 512, 512, h, h, 512, 512);
    ln_kernel<<<M_ROWS / 4, 256, 0, stream>>>(h, ab, ln1_g + (size_t)i * 512,
                                              ln1_b + (size_t)i * 512);
    gemm_bt<2><<<dim3(11, 129), 256, 0, stream>>>(
        ab, W0T + (size_t)i * 1408 * 512, b0 + (size_t)i * 1364, 1364, nullptr, regl, 512, 1408);
    gemm_bt<1><<<dim3(4, 129), 256, 0, stream>>>(
        regl, W1T + (size_t)i * 512 * 704, b1 + (size_t)i * 512, 512, h, h, 704, 512);
  }

  out_copy<<<128, 256, 0, stream>>>(h, (float*)d_out);
}

// Round 3
// 1411.832 us; speedup vs baseline: 1.2424x; 1.0685x over previous
//
#include <hip/hip_runtime.h>
#include <hip/hip_bf16.h>
#include <stdint.h>

// FT-Transformer forward, MI355X gfx950. Round 3:
//  - GEMM K-loop restructured: triple-buffered LDS, depth-2 global_load_lds prefetch,
//    ONE raw s_barrier per iter, manual s_waitcnt vmcnt(4) (never a full drain mid-loop).
//    This attacks the measured latency-bound profile (MfmaUtil 17.5%, Occ 21%).
//  - everything else identical to round 2 (swizzle, XCD remap, fused ReGLU, wave-LN).

typedef __hip_bfloat16 bf16_t;
typedef __attribute__((ext_vector_type(8))) __bf16 bf16x8;
typedef __attribute__((ext_vector_type(4))) float floatx4;

#define AS1 __attribute__((address_space(1)))
#define AS3 __attribute__((address_space(3)))

constexpr int M_ROWS = 16512;          // 128 * 129
constexpr float SQRT_EMB_F = 22.627416997969522f;  // scores DIVIDED by emb**-0.5

__device__ __forceinline__ void gload_lds16(const void* g, void* l) {
  __builtin_amdgcn_global_load_lds((const AS1 unsigned int*)g, (AS3 unsigned int*)l, 16, 0, 0);
}

__device__ __forceinline__ floatx4 mfma16(bf16x8 a, bf16x8 b, floatx4 c) {
  return __builtin_amdgcn_mfma_f32_16x16x32_bf16(a, b, c, 0, 0, 0);
}

__device__ __forceinline__ void block_barrier() {
  asm volatile("" ::: "memory");
  __builtin_amdgcn_s_barrier();
  asm volatile("" ::: "memory");
}

// ---------------- weight transpose + fp32->bf16 convert ----------------
// W [L][K][N] fp32 -> WT [L][NP][KP] bf16, zero-padded.
// PERM=1: output col n maps to source col (n&1) ? 682+(n>>1) : (n>>1)  (ReGLU pairing)
template <int PERM>
__global__ __launch_bounds__(256) void transpose_cvt(const float* __restrict__ W,
    bf16_t* __restrict__ WT, int K, int N, int KP, int NP)
{
  __shared__ float tile[32][33];
  int k0 = blockIdx.x * 32, n0 = blockIdx.y * 32;
  const float* Wl = W + (size_t)blockIdx.z * K * N;
  bf16_t* WTl = WT + (size_t)blockIdx.z * NP * KP;
  #pragma unroll
  for (int r = 0; r < 32; r += 8) {
    int k = k0 + threadIdx.y + r, n = n0 + threadIdx.x;
    int srcn = PERM ? ((n & 1) ? 682 + (n >> 1) : (n >> 1)) : n;
    int valid = (k < K) && (PERM ? (n < 1364) : (n < N));
    tile[threadIdx.y + r][threadIdx.x] = valid ? Wl[(size_t)k * N + srcn] : 0.f;
  }
  __syncthreads();
  #pragma unroll
  for (int r = 0; r < 32; r += 8) {
    int n = n0 + threadIdx.y + r, k = k0 + threadIdx.x;
    if (n < NP && k < KP)
      WTl[(size_t)n * KP + k] = __float2bfloat16(tile[threadIdx.x][threadIdx.y + r]);
  }
}

// ---------------- feature tokenizer (writes fp32 h AND bf16 ab for layer 0) ----------------
__global__ __launch_bounds__(256) void tokenizer_kernel(const float* __restrict__ x,
    const float* __restrict__ tok_w, const float* __restrict__ tok_b,
    const float* __restrict__ cat_emb, float* __restrict__ h, bf16_t* __restrict__ ab)
{
  int row = blockIdx.x;           // 0..16511
  int b = row / 129, t = row - b * 129;
  float* hr = h + (size_t)row * 512;
  bf16_t* ar = ab + (size_t)row * 512;
  for (int e = threadIdx.x; e < 512; e += 256) {
    float val;
    if (t == 0) {
      val = tok_w[e];
    } else if (t <= 100) {
      val = tok_w[(size_t)t * 512 + e] * x[(size_t)b * 128 + 28 + (t - 1)]
            + tok_b[(size_t)(t - 1) * 512 + e];
    } else {
      int j = t - 101;
      int idx = (int)x[(size_t)b * 128 + j] + 100 * j;
      val = cat_emb[(size_t)idx * 512 + e] + tok_b[(size_t)(t - 1) * 512 + e];
    }
    hr[e] = val;
    ar[e] = __float2bfloat16(val);
  }
}

// ---------------- layernorm: one 64-lane wave per row, no LDS ----------------
__global__ __launch_bounds__(256) void ln_kernel(const float* __restrict__ hin,
    bf16_t* __restrict__ out, const float* __restrict__ g, const float* __restrict__ bta)
{
  int row = blockIdx.x * 4 + (threadIdx.x >> 6);
  int lane = threadIdx.x & 63;
  const float* hr = hin + (size_t)row * 512 + lane * 8;
  float4 v0 = *(const float4*)hr;
  float4 v1 = *(const float4*)(hr + 4);
  float s = v0.x + v0.y + v0.z + v0.w + v1.x + v1.y + v1.z + v1.w;
  float q = v0.x * v0.x + v0.y * v0.y + v0.z * v0.z + v0.w * v0.w
          + v1.x * v1.x + v1.y * v1.y + v1.z * v1.z + v1.w * v1.w;
  #pragma unroll
  for (int o = 1; o < 64; o <<= 1) { s += __shfl_xor(s, o); q += __shfl_xor(q, o); }
  float mean = s * (1.f / 512.f);
  float var = q * (1.f / 512.f) - mean * mean;
  float rstd = rsqrtf(var + 1e-5f);
  float4 g0 = *(const float4*)(g + lane * 8);
  float4 g1 = *(const float4*)(g + lane * 8 + 4);
  float4 b0v = *(const float4*)(bta + lane * 8);
  float4 b1v = *(const float4*)(bta + lane * 8 + 4);
  bf16x8 o8;
  o8[0] = (__bf16)__float2bfloat16((v0.x - mean) * rstd * g0.x + b0v.x);
  o8[1] = (__bf16)__float2bfloat16((v0.y - mean) * rstd * g0.y + b0v.y);
  o8[2] = (__bf16)__float2bfloat16((v0.z - mean) * rstd * g0.z + b0v.z);
  o8[3] = (__bf16)__float2bfloat16((v0.w - mean) * rstd * g0.w + b0v.w);
  o8[4] = (__bf16)__float2bfloat16((v1.x - mean) * rstd * g1.x + b1v.x);
  o8[5] = (__bf16)__float2bfloat16((v1.y - mean) * rstd * g1.y + b1v.y);
  o8[6] = (__bf16)__float2bfloat16((v1.z - mean) * rstd * g1.z + b1v.z);
  o8[7] = (__bf16)__float2bfloat16((v1.w - mean) * rstd * g1.w + b1v.w);
  *(bf16x8*)(out + (size_t)row * 512 + lane * 8) = o8;
}

// ---------------- GEMM: C[M,N] = A[M,K](bf16) * BT[N,K]^T + bias ----------------
// MODE 0: bf16 out.  MODE 1: fp32 out = resid + acc + bias.
// MODE 2: ReGLU out bf16 [M, N/2]: paired cols (a=even, b=odd), out = a*relu(b).
// K-loop: triple-buffered LDS, depth-2 prefetch, 1 barrier/iter, vmcnt(4) waits.
template <int MODE>
__global__ __launch_bounds__(256) void gemm_bt(const bf16_t* __restrict__ A,
    const bf16_t* __restrict__ BT, const float* __restrict__ bias, int biasN,
    const float* __restrict__ resid, void* __restrict__ outp, int K, int N)
{
  __shared__ bf16_t As[3][128 * 32];
  __shared__ bf16_t Bs[3][128 * 32];
  // XCD-aware remap: blocks with lin%8==x get a contiguous idx chunk -> contiguous m range
  const int total = gridDim.x * gridDim.y;
  const int lin = blockIdx.y * gridDim.x + blockIdx.x;
  const int xcd = lin & 7, kb = lin >> 3;
  const int qch = total >> 3, rch = total & 7;
  const int idx = xcd * qch + (xcd < rch ? xcd : rch) + kb;
  const int bm = idx / gridDim.x;
  const int bn = idx - bm * gridDim.x;
  const int m0 = bm * 128, n0 = bn * 128;

  const int tid = threadIdx.x;
  const int w = tid >> 6, l = tid & 63, l15 = l & 15, quad = l >> 4;
  const int wm = (w >> 1) * 64, wn = (w & 1) * 64;
  const bf16_t* Ab = A + (size_t)m0 * K;
  const bf16_t* Bb = BT + (size_t)n0 * K;
  const int r0 = tid >> 2;
  const int kc0 = (((tid & 3) ^ ((tid >> 3) & 3))) * 8;  // XOR-swizzled chunk
  const int swz = (l15 >> 1) & 3;                        // read-side swizzle
  const size_t a0o = (size_t)r0 * K + kc0;
  const size_t a1o = (size_t)(r0 + 64) * K + kc0;

  auto issue = [&](int t, int buf) {
    const int kk = t * 32;
    gload_lds16(Ab + a0o + kk, &As[buf][tid * 8]);
    gload_lds16(Ab + a1o + kk, &As[buf][(tid + 256) * 8]);
    gload_lds16(Bb + a0o + kk, &Bs[buf][tid * 8]);
    gload_lds16(Bb + a1o + kk, &Bs[buf][(tid + 256) * 8]);
  };

  floatx4 z4 = {0.f, 0.f, 0.f, 0.f};
  floatx4 acc[4][4];
  #pragma unroll
  for (int i = 0; i < 4; i++)
    #pragma unroll
    for (int j = 0; j < 4; j++) acc[i][j] = z4;

  const int T = K >> 5;
  issue(0, 0);
  issue(1, 1);
  int cur = 0, nxt2 = 2;
  for (int t = 0; t < T; t++) {
    // wait for tile t (my 4 oldest loads); tile t+1's stay in flight
    if (t + 1 < T) __builtin_amdgcn_s_waitcnt(0x0F74);   // vmcnt(4)
    else           __builtin_amdgcn_s_waitcnt(0x0F70);   // vmcnt(0)
    block_barrier();   // all waves' tile-t data landed; all reads of buf nxt2 done at t-1
    if (t + 2 < T) issue(t + 2, nxt2);
    const bf16_t* Ac = As[cur];
    const bf16_t* Bc = Bs[cur];
    bf16x8 af[4], bfr[4];
    #pragma unroll
    for (int i = 0; i < 4; i++) {
      af[i]  = *(const bf16x8*)&Ac[(wm + i * 16 + l15) * 32 + ((quad ^ swz) * 8)];
      bfr[i] = *(const bf16x8*)&Bc[(wn + i * 16 + l15) * 32 + ((quad ^ swz) * 8)];
    }
    #pragma unroll
    for (int i = 0; i < 4; i++)
      #pragma unroll
      for (int j = 0; j < 4; j++)
        acc[i][j] = mfma16(af[i], bfr[j], acc[i][j]);
    cur = (cur == 2) ? 0 : cur + 1;
    nxt2 = (nxt2 == 2) ? 0 : nxt2 + 1;
  }

  #pragma unroll
  for (int j = 0; j < 4; j++) {
    int col = n0 + wn + j * 16 + l15;
    float bv = 0.f;
    if (MODE == 2) {
      if (col < biasN) bv = bias[(col & 1) ? 682 + (col >> 1) : (col >> 1)];
    } else {
      if (col < biasN) bv = bias[col];
    }
    #pragma unroll
    for (int i = 0; i < 4; i++) {
      int row_b = m0 + wm + i * 16 + quad * 4;
      #pragma unroll
      for (int r = 0; r < 4; r++) {
        float v = acc[i][j][r] + bv;
        if (MODE == 2) {
          float other = __shfl_xor(v, 1);
          if (!(l15 & 1)) {
            size_t idx2 = (size_t)(row_b + r) * (N >> 1) + (col >> 1);
            ((bf16_t*)outp)[idx2] = __float2bfloat16(v * fmaxf(other, 0.f));
          }
        } else {
          size_t idx2 = (size_t)(row_b + r) * N + col;
          if (MODE == 1) ((float*)outp)[idx2] = v + resid[idx2];
          else           ((bf16_t*)outp)[idx2] = __float2bfloat16(v);
        }
      }
    }
  }
}

// ---------------- fused attention: one block per (batch, head) ----------------
constexpr int SP = 160;  // S=129 padded to 5*32
__global__ __launch_bounds__(256) void attn_kernel(const bf16_t* __restrict__ qkv,
                                                   bf16_t* __restrict__ attnout)
{
  __shared__ bf16_t vt_lds[64 * SP];   // [d][s_kv]
  __shared__ float sc[32 * SP];        // scores for one 32-row q tile; p (bf16) overlays
  bf16_t* p_lds = (bf16_t*)sc;

  const int bh = blockIdx.x, b = bh >> 3, hh = bh & 7;
  const int tid = threadIdx.x;
  const int w = tid >> 6, l = tid & 63, l15 = l & 15, quad = l >> 4;
  const bf16_t* base = qkv + (size_t)b * 129 * 1536 + hh * 192;

  for (int i = tid; i < SP * 64 / 2; i += 256) ((unsigned int*)vt_lds)[i] = 0u;
  __syncthreads();
  for (int c = tid; c < 129 * 8; c += 256) {
    int s = c >> 3, ch = c & 7;
    float4 tmp4 = *(const float4*)(base + (size_t)s * 1536 + 128 + ch * 8);
    const bf16_t* tv = (const bf16_t*)&tmp4;
    #pragma unroll
    for (int j = 0; j < 8; j++) vt_lds[(size_t)(ch * 8 + j) * SP + s] = tv[j];
  }
  __syncthreads();

  for (int qt = 0; qt < 5; qt++) {
    bf16x8 zq = {};
    bf16x8 aq[2][2];
    #pragma unroll
    for (int mt = 0; mt < 2; mt++) {
      int m = qt * 32 + mt * 16 + l15;
      #pragma unroll
      for (int t = 0; t < 2; t++)
        aq[mt][t] = (m < 129) ? *(const bf16x8*)(base + (size_t)m * 1536 + t * 32 + quad * 8) : zq;
    }
    for (int nt = w; nt < 10; nt += 4) {
      int krow = nt * 16 + l15;
      floatx4 a0 = {0.f, 0.f, 0.f, 0.f}, a1 = {0.f, 0.f, 0.f, 0.f};
      #pragma unroll
      for (int t = 0; t < 2; t++) {
        bf16x8 kf = (krow < 129)
            ? *(const bf16x8*)(base + (size_t)krow * 1536 + 64 + t * 32 + quad * 8) : zq;
        a0 = mfma16(aq[0][t], kf, a0);
        a1 = mfma16(aq[1][t], kf, a1);
      }
      #pragma unroll
      for (int r = 0; r < 4; r++) {
        sc[(quad * 4 + r) * SP + nt * 16 + l15]      = a0[r] * SQRT_EMB_F;
        sc[(16 + quad * 4 + r) * SP + nt * 16 + l15] = a1[r] * SQRT_EMB_F;
      }
    }
    __syncthreads();

    // double softmax, 8 threads per row
    {
      int row = tid >> 3, sub = tid & 7;
      float vv[20];
      float mx = -1e30f;
      #pragma unroll
      for (int c = 0; c < 20; c++) {
        int j = sub + c * 8;
        vv[c] = (j < 129) ? sc[row * SP + j] : -1e30f;
        mx = fmaxf(mx, vv[c]);
      }
      #pragma unroll
      for (int o = 1; o < 8; o <<= 1) mx = fmaxf(mx, __shfl_xor(mx, o, 8));
      float sum = 0.f;
      #pragma unroll
      for (int c = 0; c < 20; c++) {
        int j = sub + c * 8;
        vv[c] = (j < 129) ? __expf(vv[c] - mx) : 0.f;
        sum += vv[c];
      }
      #pragma unroll
      for (int o = 1; o < 8; o <<= 1) sum += __shfl_xor(sum, o, 8);
      float inv = 1.f / sum;
      float mx2 = 0.f;
      #pragma unroll
      for (int c = 0; c < 20; c++) { vv[c] *= inv; mx2 = fmaxf(mx2, vv[c]); }
      #pragma unroll
      for (int o = 1; o < 8; o <<= 1) mx2 = fmaxf(mx2, __shfl_xor(mx2, o, 8));
      float sum2 = 0.f;
      #pragma unroll
      for (int c = 0; c < 20; c++) {
        int j = sub + c * 8;
        vv[c] = (j < 129) ? __expf(vv[c] - mx2) : 0.f;
        sum2 += vv[c];
      }
      #pragma unroll
      for (int o = 1; o < 8; o <<= 1) sum2 += __shfl_xor(sum2, o, 8);
      float inv2 = 1.f / sum2;
      __syncthreads();  // all reads of sc done before bf16 overlay write
      #pragma unroll
      for (int c = 0; c < 20; c++) {
        int j = sub + c * 8;
        p_lds[row * SP + j] = __float2bfloat16(vv[c] * inv2);  // pads -> 0
      }
    }
    __syncthreads();

    // PV: o[32,64] = p[32,160] @ v[160,64]
    {
      int mt = w >> 1, nt0 = (w & 1) * 2;
      floatx4 oacc[2];
      oacc[0] = floatx4{0.f, 0.f, 0.f, 0.f};
      oacc[1] = floatx4{0.f, 0.f, 0.f, 0.f};
      #pragma unroll
      for (int t = 0; t < 5; t++) {
        bf16x8 pf = *(const bf16x8*)&p_lds[(mt * 16 + l15) * SP + t * 32 + quad * 8];
        #pragma unroll
        for (int n = 0; n < 2; n++) {
          bf16x8 vf = *(const bf16x8*)&vt_lds[((nt0 + n) * 16 + l15) * SP + t * 32 + quad * 8];
          oacc[n] = mfma16(pf, vf, oacc[n]);
        }
      }
      #pragma unroll
      for (int n = 0; n < 2; n++)
        #pragma unroll
        for (int r = 0; r < 4; r++) {
          int sq = qt * 32 + mt * 16 + quad * 4 + r;
          if (sq < 129)
            attnout[((size_t)b * 129 + sq) * 512 + hh * 64 + (nt0 + n) * 16 + l15] =
                __float2bfloat16(oacc[n][r]);
        }
    }
    __syncthreads();
  }
}

// ---------------- output: CLS rows ----------------
__global__ __launch_bounds__(256) void out_copy(const float* __restrict__ h,
                                                float* __restrict__ out)
{
  int b = blockIdx.x, e = threadIdx.x;
  out[(size_t)b * 512 + e]       = h[(size_t)b * 129 * 512 + e];
  out[(size_t)b * 512 + e + 256] = h[(size_t)b * 129 * 512 + e + 256];
}

// ---------------- host launcher ----------------
extern "C" void kernel_launch(void* const* d_in, const int* in_sizes, int n_in,
                              void* d_out, int out_size, void* d_ws, size_t ws_size,
                              hipStream_t stream)
{
  const float* x       = (const float*)d_in[0];
  const float* tok_w   = (const float*)d_in[1];
  const float* tok_b   = (const float*)d_in[2];
  const float* cat_emb = (const float*)d_in[3];
  const float* Wqkv    = (const float*)d_in[4];
  const float* bqkv    = (const float*)d_in[5];
  const float* Wout    = (const float*)d_in[6];
  const float* bout    = (const float*)d_in[7];
  const float* W0      = (const float*)d_in[8];
  const float* b0      = (const float*)d_in[9];
  const float* W1      = (const float*)d_in[10];
  const float* b1      = (const float*)d_in[11];
  const float* ln0_g   = (const float*)d_in[12];
  const float* ln0_b   = (const float*)d_in[13];
  const float* ln1_g   = (const float*)d_in[14];
  const float* ln1_b   = (const float*)d_in[15];

  size_t off = 0;
  char* base = (char*)d_ws;
  auto alloc = [&](size_t n) { char* p = base + off; off += (n + 255) & ~(size_t)255; return p; };
  float*  h     = (float*) alloc((size_t)M_ROWS * 512 * 4);
  bf16_t* ab    = (bf16_t*)alloc((size_t)M_ROWS * 512 * 2);   // LN outputs (GEMM A)
  bf16_t* qkv   = (bf16_t*)alloc((size_t)M_ROWS * 1536 * 2);
  bf16_t* attno = (bf16_t*)alloc((size_t)M_ROWS * 512 * 2);
  bf16_t* regl  = (bf16_t*)alloc((size_t)M_ROWS * 704 * 2);
  bf16_t* WqkvT = (bf16_t*)alloc((size_t)6 * 1536 * 512 * 2);
  bf16_t* WoutT = (bf16_t*)alloc((size_t)6 * 512 * 512 * 2);
  bf16_t* W0T   = (bf16_t*)alloc((size_t)6 * 1408 * 512 * 2);  // pair-interleaved
  bf16_t* W1T   = (bf16_t*)alloc((size_t)6 * 512 * 704 * 2);
  (void)ws_size; (void)in_sizes; (void)n_in; (void)out_size;

  dim3 tb(32, 8, 1);
  transpose_cvt<0><<<dim3(16, 48, 6), tb, 0, stream>>>(Wqkv, WqkvT, 512, 1536, 512, 1536);
  transpose_cvt<0><<<dim3(16, 16, 6), tb, 0, stream>>>(Wout, WoutT, 512, 512, 512, 512);
  transpose_cvt<1><<<dim3(16, 44, 6), tb, 0, stream>>>(W0, W0T, 512, 1364, 512, 1408);
  transpose_cvt<0><<<dim3(22, 16, 6), tb, 0, stream>>>(W1, W1T, 682, 512, 704, 512);

  tokenizer_kernel<<<M_ROWS, 256, 0, stream>>>(x, tok_w, tok_b, cat_emb, h, ab);

  for (int i = 0; i < 6; i++) {
    if (i)
      ln_kernel<<<M_ROWS / 4, 256, 0, stream>>>(h, ab, ln0_g + (size_t)i * 512,
                                                ln0_b + (size_t)i * 512);
    gemm_bt<0><<<dim3(12, 129), 256, 0, stream>>>(
        ab, WqkvT + (size_t)i * 1536 * 512, bqkv + (size_t)i * 1536, 1536, nullptr, qkv, 512, 1536);
    attn_kernel<<<1024, 256, 0, stream>>>(qkv, attno);
    gemm_bt<1><<<dim3(4, 129), 256, 0, stream>>>(
        attno, WoutT + (size_t)i * 512 * 512, bout + (size_t)i * 512, 512, h, h, 512, 512);
    ln_kernel<<<M_ROWS / 4, 256, 0, stream>>>(h, ab, ln1_g + (size_t)i * 512,
                                              ln1_b + (size_t)i * 512);
    gemm_bt<2><<<dim3(11, 129), 256, 0, stream>>>(
        ab, W0T + (size_t)i * 1408 * 512, b0 + (size_t)i * 1364, 1364, nullptr, regl, 512, 1408);
    gemm_bt<1><<<dim3(4, 129), 256, 0, stream>>>(
        regl, W1T + (size_t)i * 512 * 704, b1 + (size_t)i * 512, 512, h, h, 704, 512);
  }

  out_copy<<<128, 256, 0, stream>>>(h, (float*)d_out);
}

// Round 5
// 1273.075 us; speedup vs baseline: 1.3778x; 1.1090x over previous
//
#include <hip/hip_runtime.h>
#include <hip/hip_bf16.h>
#include <stdint.h>

// FT-Transformer forward, MI355X gfx950. Round 5 (= round 4 + compile fix):
//  - GEMMs "flatmm-style": ALL operands stored in MFMA fragment-tiled layout
//    (16x32 tile = 512 bf16 contiguous; lane l's 16B chunk at tile+l*8). Inner loop is
//    global_load_dwordx4 -> registers (double-buffered) + MFMA. NO LDS, NO barriers.
//  - producers (tokenizer, LN, attn epilogue, GEMM epilogues, weight transform) write
//    fragment layout directly; attention computes per-lane fragment addresses.
//  - fix vs round 4: vt_lds stores through __bf16* view (raw __bf16 -> __hip_bfloat16
//    assignment is ambiguous in ROCm 7.2 headers).

typedef __hip_bfloat16 bf16_t;
typedef __attribute__((ext_vector_type(8))) __bf16 bf16x8;
typedef __attribute__((ext_vector_type(4))) float floatx4;

constexpr int M_ROWS = 16512;          // 128 * 129
constexpr float SQRT_EMB_F = 22.627416997969522f;  // scores DIVIDED by emb**-0.5

__device__ __forceinline__ floatx4 mfma16(bf16x8 a, bf16x8 b, floatx4 c) {
  return __builtin_amdgcn_mfma_f32_16x16x32_bf16(a, b, c, 0, 0, 0);
}

// element offset of the 16B chunk holding (m, k..k+7) in fragment-tiled [M/16][KT][512]
__device__ __forceinline__ size_t frag_chunk(int m, int k, int KT) {
  return ((size_t)(m >> 4) * KT + (k >> 5)) * 512 + (m & 15) * 8 + 128 * ((k >> 3) & 3);
}
// element offset of scalar (m, k)
__device__ __forceinline__ size_t frag_elem(int m, int k, int KT) {
  return frag_chunk(m, k, KT) + (k & 7);
}

// ---------------- weight transform: W [L][K][N] fp32 -> frag-tiled bf16 [L][N/16][KP/32][512]
// PERM=1: output col n maps to source col (n&1) ? 682+(n>>1) : (n>>1)  (ReGLU pairing)
template <int PERM>
__global__ __launch_bounds__(256) void transpose_cvt(const float* __restrict__ W,
    bf16_t* __restrict__ WT, int K, int N, int KP, int NP)
{
  __shared__ float tile[32][33];
  int k0 = blockIdx.x * 32, n0 = blockIdx.y * 32;
  const float* Wl = W + (size_t)blockIdx.z * K * N;
  bf16_t* WTl = WT + (size_t)blockIdx.z * NP * KP;
  const int KT = KP >> 5;
  #pragma unroll
  for (int r = 0; r < 32; r += 8) {
    int k = k0 + threadIdx.y + r, n = n0 + threadIdx.x;
    int srcn = PERM ? ((n & 1) ? 682 + (n >> 1) : (n >> 1)) : n;
    int valid = (k < K) && (PERM ? (n < 1364) : (n < N));
    tile[threadIdx.y + r][threadIdx.x] = valid ? Wl[(size_t)k * N + srcn] : 0.f;
  }
  __syncthreads();
  #pragma unroll
  for (int r = 0; r < 32; r += 8) {
    int n = n0 + threadIdx.y + r, k = k0 + threadIdx.x;
    if (n < NP && k < KP)
      WTl[frag_elem(n, k, KT)] = __float2bfloat16(tile[threadIdx.x][threadIdx.y + r]);
  }
}

// ---------------- feature tokenizer: wave per row; h row-major fp32 + ab frag bf16 ----------------
__global__ __launch_bounds__(256) void tokenizer_kernel(const float* __restrict__ x,
    const float* __restrict__ tok_w, const float* __restrict__ tok_b,
    const float* __restrict__ cat_emb, float* __restrict__ h, bf16_t* __restrict__ ab)
{
  int row = blockIdx.x * 4 + (threadIdx.x >> 6);
  int lane = threadIdx.x & 63, e0 = lane * 8;
  int b = row / 129, t = row - b * 129;
  float v[8];
  if (t == 0) {
    #pragma unroll
    for (int u = 0; u < 8; u++) v[u] = tok_w[e0 + u];
  } else if (t <= 100) {
    float xv = x[(size_t)b * 128 + 28 + (t - 1)];
    const float* wp = tok_w + (size_t)t * 512 + e0;
    const float* bp = tok_b + (size_t)(t - 1) * 512 + e0;
    #pragma unroll
    for (int u = 0; u < 8; u++) v[u] = wp[u] * xv + bp[u];
  } else {
    int j = t - 101;
    int idx = (int)x[(size_t)b * 128 + j] + 100 * j;
    const float* cp = cat_emb + (size_t)idx * 512 + e0;
    const float* bp = tok_b + (size_t)(t - 1) * 512 + e0;
    #pragma unroll
    for (int u = 0; u < 8; u++) v[u] = cp[u] + bp[u];
  }
  float* hr = h + (size_t)row * 512 + e0;
  #pragma unroll
  for (int u = 0; u < 8; u++) hr[u] = v[u];
  bf16x8 o8;
  #pragma unroll
  for (int u = 0; u < 8; u++) o8[u] = (__bf16)__float2bfloat16(v[u]);
  *(bf16x8*)(ab + ((size_t)(row >> 4) * 16 + (lane >> 2)) * 512 + (row & 15) * 8 + 128 * (lane & 3)) = o8;
}

// ---------------- layernorm: one wave per row; out = frag-tiled bf16 (KT=16) ----------------
__global__ __launch_bounds__(256) void ln_kernel(const float* __restrict__ hin,
    bf16_t* __restrict__ out, const float* __restrict__ g, const float* __restrict__ bta)
{
  int row = blockIdx.x * 4 + (threadIdx.x >> 6);
  int lane = threadIdx.x & 63;
  const float* hr = hin + (size_t)row * 512 + lane * 8;
  float4 v0 = *(const float4*)hr;
  float4 v1 = *(const float4*)(hr + 4);
  float s = v0.x + v0.y + v0.z + v0.w + v1.x + v1.y + v1.z + v1.w;
  float q = v0.x * v0.x + v0.y * v0.y + v0.z * v0.z + v0.w * v0.w
          + v1.x * v1.x + v1.y * v1.y + v1.z * v1.z + v1.w * v1.w;
  #pragma unroll
  for (int o = 1; o < 64; o <<= 1) { s += __shfl_xor(s, o); q += __shfl_xor(q, o); }
  float mean = s * (1.f / 512.f);
  float var = q * (1.f / 512.f) - mean * mean;
  float rstd = rsqrtf(var + 1e-5f);
  float4 g0 = *(const float4*)(g + lane * 8);
  float4 g1 = *(const float4*)(g + lane * 8 + 4);
  float4 b0v = *(const float4*)(bta + lane * 8);
  float4 b1v = *(const float4*)(bta + lane * 8 + 4);
  bf16x8 o8;
  o8[0] = (__bf16)__float2bfloat16((v0.x - mean) * rstd * g0.x + b0v.x);
  o8[1] = (__bf16)__float2bfloat16((v0.y - mean) * rstd * g0.y + b0v.y);
  o8[2] = (__bf16)__float2bfloat16((v0.z - mean) * rstd * g0.z + b0v.z);
  o8[3] = (__bf16)__float2bfloat16((v0.w - mean) * rstd * g0.w + b0v.w);
  o8[4] = (__bf16)__float2bfloat16((v1.x - mean) * rstd * g1.x + b1v.x);
  o8[5] = (__bf16)__float2bfloat16((v1.y - mean) * rstd * g1.y + b1v.y);
  o8[6] = (__bf16)__float2bfloat16((v1.z - mean) * rstd * g1.z + b1v.z);
  o8[7] = (__bf16)__float2bfloat16((v1.w - mean) * rstd * g1.w + b1v.w);
  *(bf16x8*)(out + ((size_t)(row >> 4) * 16 + (lane >> 2)) * 512 + (row & 15) * 8 + 128 * (lane & 3)) = o8;
}

// ---------------- frag GEMM: C[M,N] = A * BT^T + bias, no LDS, no barriers ----------------
// A frag-tiled [M/16][K/32][512]; BT frag-tiled [N/16][K/32][512].
// MODE 0: out bf16 frag-tiled (KT_out = N/32).
// MODE 1: out fp32 row-major = resid + acc + bias (N==512).
// MODE 2: ReGLU: paired cols (a=even,b=odd), out bf16 frag-tiled [M/16][(N/2)/32][512].
template <int MODE>
__global__ __launch_bounds__(256, 3) void gemm_frag(const bf16_t* __restrict__ A,
    const bf16_t* __restrict__ BT, const float* __restrict__ bias, int biasN,
    const float* __restrict__ resid, void* __restrict__ outp, int K, int N)
{
  // XCD-aware remap: blocks with lin%8==x get a contiguous idx chunk
  const int total = gridDim.x * gridDim.y;
  const int lin = blockIdx.y * gridDim.x + blockIdx.x;
  const int xcd = lin & 7, kb2 = lin >> 3;
  const int qch = total >> 3, rch = total & 7;
  const int idx = xcd * qch + (xcd < rch ? xcd : rch) + kb2;
  const int bm = idx / gridDim.x;
  const int bn = idx - bm * gridDim.x;
  const int m0 = bm * 128, n0 = bn * 128;

  const int tid = threadIdx.x;
  const int w = tid >> 6, l = tid & 63, l15 = l & 15, quad = l >> 4;
  const int wm = (w >> 1) * 64, wn = (w & 1) * 64;
  const int KT = K >> 5;

  const bf16_t* pa[4];
  const bf16_t* pb[4];
  #pragma unroll
  for (int i = 0; i < 4; i++) {
    pa[i] = A  + ((size_t)(((m0 + wm) >> 4) + i) * KT) * 512 + l * 8;
    pb[i] = BT + ((size_t)(((n0 + wn) >> 4) + i) * KT) * 512 + l * 8;
  }

  bf16x8 af[2][4], bg[2][4];
  #pragma unroll
  for (int i = 0; i < 4; i++) {
    af[0][i] = *(const bf16x8*)pa[i];
    bg[0][i] = *(const bf16x8*)pb[i];
  }

  floatx4 z4 = {0.f, 0.f, 0.f, 0.f};
  floatx4 acc[4][4];
  #pragma unroll
  for (int i = 0; i < 4; i++)
    #pragma unroll
    for (int j = 0; j < 4; j++) acc[i][j] = z4;

  const int T = KT;  // 16 or 22, always even
  for (int t = 0; t < T; t += 2) {
    if (t + 1 < T) {
      #pragma unroll
      for (int i = 0; i < 4; i++) {
        af[1][i] = *(const bf16x8*)(pa[i] + (size_t)(t + 1) * 512);
        bg[1][i] = *(const bf16x8*)(pb[i] + (size_t)(t + 1) * 512);
      }
    }
    #pragma unroll
    for (int i = 0; i < 4; i++)
      #pragma unroll
      for (int j = 0; j < 4; j++)
        acc[i][j] = mfma16(af[0][i], bg[0][j], acc[i][j]);
    if (t + 1 < T) {
      if (t + 2 < T) {
        #pragma unroll
        for (int i = 0; i < 4; i++) {
          af[0][i] = *(const bf16x8*)(pa[i] + (size_t)(t + 2) * 512);
          bg[0][i] = *(const bf16x8*)(pb[i] + (size_t)(t + 2) * 512);
        }
      }
      #pragma unroll
      for (int i = 0; i < 4; i++)
        #pragma unroll
        for (int j = 0; j < 4; j++)
          acc[i][j] = mfma16(af[1][i], bg[1][j], acc[i][j]);
    }
  }

  #pragma unroll
  for (int j = 0; j < 4; j++) {
    int col = n0 + wn + j * 16 + l15;
    float bv = 0.f;
    if (MODE == 2) {
      if (col < biasN) bv = bias[(col & 1) ? 682 + (col >> 1) : (col >> 1)];
    } else {
      if (col < biasN) bv = bias[col];
    }
    #pragma unroll
    for (int i = 0; i < 4; i++) {
      int row_b = m0 + wm + i * 16 + quad * 4;
      #pragma unroll
      for (int r = 0; r < 4; r++) {
        float v = acc[i][j][r] + bv;
        int m = row_b + r;
        if (MODE == 2) {
          float other = __shfl_xor(v, 1);
          if (!(l15 & 1)) {
            int c2 = col >> 1;
            ((bf16_t*)outp)[frag_elem(m, c2, (N >> 1) >> 5)] =
                __float2bfloat16(v * fmaxf(other, 0.f));
          }
        } else if (MODE == 1) {
          size_t idx2 = (size_t)m * N + col;
          ((float*)outp)[idx2] = v + resid[idx2];
        } else {
          ((bf16_t*)outp)[frag_elem(m, col, N >> 5)] = __float2bfloat16(v);
        }
      }
    }
  }
}

// ---------------- fused attention: one block per (batch, head) ----------------
// qkv frag-tiled over [M, 1536] (KT=48); head hh: q at col hh*192, k +64, v +128.
constexpr int SP = 160;  // S=129 padded to 5*32
__global__ __launch_bounds__(256) void attn_kernel(const bf16_t* __restrict__ qkv,
                                                   bf16_t* __restrict__ attnout)
{
  __shared__ bf16_t vt_lds[64 * SP];   // [d][s_kv]
  __shared__ float sc[32 * SP];        // scores; p (bf16) overlays
  bf16_t* p_lds = (bf16_t*)sc;
  __bf16* vt_raw = (__bf16*)vt_lds;

  const int bh = blockIdx.x, b = bh >> 3, hh = bh & 7;
  const int tid = threadIdx.x;
  const int w = tid >> 6, l = tid & 63, l15 = l & 15, quad = l >> 4;
  const int rbase = b * 129;

  for (int i = tid; i < SP * 64 / 2; i += 256) ((unsigned int*)vt_lds)[i] = 0u;
  __syncthreads();
  for (int c = tid; c < 129 * 8; c += 256) {
    int s = c >> 3, ch = c & 7;
    bf16x8 tv = *(const bf16x8*)(qkv + frag_chunk(rbase + s, hh * 192 + 128 + ch * 8, 48));
    #pragma unroll
    for (int j = 0; j < 8; j++) vt_raw[(size_t)(ch * 8 + j) * SP + s] = tv[j];
  }
  __syncthreads();

  for (int qt = 0; qt < 5; qt++) {
    bf16x8 zq = {};
    bf16x8 aq[2][2];
    #pragma unroll
    for (int mt = 0; mt < 2; mt++) {
      int m = qt * 32 + mt * 16 + l15;
      #pragma unroll
      for (int t = 0; t < 2; t++)
        aq[mt][t] = (m < 129)
            ? *(const bf16x8*)(qkv + frag_chunk(rbase + m, hh * 192 + t * 32 + quad * 8, 48)) : zq;
    }
    for (int nt = w; nt < 10; nt += 4) {
      int krow = nt * 16 + l15;
      floatx4 a0 = {0.f, 0.f, 0.f, 0.f}, a1 = {0.f, 0.f, 0.f, 0.f};
      #pragma unroll
      for (int t = 0; t < 2; t++) {
        bf16x8 kf = (krow < 129)
            ? *(const bf16x8*)(qkv + frag_chunk(rbase + krow, hh * 192 + 64 + t * 32 + quad * 8, 48))
            : zq;
        a0 = mfma16(aq[0][t], kf, a0);
        a1 = mfma16(aq[1][t], kf, a1);
      }
      #pragma unroll
      for (int r = 0; r < 4; r++) {
        sc[(quad * 4 + r) * SP + nt * 16 + l15]      = a0[r] * SQRT_EMB_F;
        sc[(16 + quad * 4 + r) * SP + nt * 16 + l15] = a1[r] * SQRT_EMB_F;
      }
    }
    __syncthreads();

    // double softmax, 8 threads per row
    {
      int row = tid >> 3, sub = tid & 7;
      float vv[20];
      float mx = -1e30f;
      #pragma unroll
      for (int c = 0; c < 20; c++) {
        int j = sub + c * 8;
        vv[c] = (j < 129) ? sc[row * SP + j] : -1e30f;
        mx = fmaxf(mx, vv[c]);
      }
      #pragma unroll
      for (int o = 1; o < 8; o <<= 1) mx = fmaxf(mx, __shfl_xor(mx, o, 8));
      float sum = 0.f;
      #pragma unroll
      for (int c = 0; c < 20; c++) {
        int j = sub + c * 8;
        vv[c] = (j < 129) ? __expf(vv[c] - mx) : 0.f;
        sum += vv[c];
      }
      #pragma unroll
      for (int o = 1; o < 8; o <<= 1) sum += __shfl_xor(sum, o, 8);
      float inv = 1.f / sum;
      float mx2 = 0.f;
      #pragma unroll
      for (int c = 0; c < 20; c++) { vv[c] *= inv; mx2 = fmaxf(mx2, vv[c]); }
      #pragma unroll
      for (int o = 1; o < 8; o <<= 1) mx2 = fmaxf(mx2, __shfl_xor(mx2, o, 8));
      float sum2 = 0.f;
      #pragma unroll
      for (int c = 0; c < 20; c++) {
        int j = sub + c * 8;
        vv[c] = (j < 129) ? __expf(vv[c] - mx2) : 0.f;
        sum2 += vv[c];
      }
      #pragma unroll
      for (int o = 1; o < 8; o <<= 1) sum2 += __shfl_xor(sum2, o, 8);
      float inv2 = 1.f / sum2;
      __syncthreads();
      #pragma unroll
      for (int c = 0; c < 20; c++) {
        int j = sub + c * 8;
        p_lds[row * SP + j] = __float2bfloat16(vv[c] * inv2);  // pads -> 0
      }
    }
    __syncthreads();

    // PV: o[32,64] = p[32,160] @ v[160,64]; store attno in frag layout (KT=16)
    {
      int mt = w >> 1, nt0 = (w & 1) * 2;
      floatx4 oacc[2];
      oacc[0] = floatx4{0.f, 0.f, 0.f, 0.f};
      oacc[1] = floatx4{0.f, 0.f, 0.f, 0.f};
      #pragma unroll
      for (int t = 0; t < 5; t++) {
        bf16x8 pf = *(const bf16x8*)&p_lds[(mt * 16 + l15) * SP + t * 32 + quad * 8];
        #pragma unroll
        for (int n = 0; n < 2; n++) {
          bf16x8 vf = *(const bf16x8*)&vt_lds[((nt0 + n) * 16 + l15) * SP + t * 32 + quad * 8];
          oacc[n] = mfma16(pf, vf, oacc[n]);
        }
      }
      #pragma unroll
      for (int n = 0; n < 2; n++)
        #pragma unroll
        for (int r = 0; r < 4; r++) {
          int sq = qt * 32 + mt * 16 + quad * 4 + r;
          if (sq < 129) {
            int cc = hh * 64 + (nt0 + n) * 16 + l15;
            attnout[frag_elem(rbase + sq, cc, 16)] = __float2bfloat16(oacc[n][r]);
          }
        }
    }
    __syncthreads();
  }
}

// ---------------- output: CLS rows ----------------
__global__ __launch_bounds__(256) void out_copy(const float* __restrict__ h,
                                                float* __restrict__ out)
{
  int b = blockIdx.x, e = threadIdx.x;
  out[(size_t)b * 512 + e]       = h[(size_t)b * 129 * 512 + e];
  out[(size_t)b * 512 + e + 256] = h[(size_t)b * 129 * 512 + e + 256];
}

// ---------------- host launcher ----------------
extern "C" void kernel_launch(void* const* d_in, const int* in_sizes, int n_in,
                              void* d_out, int out_size, void* d_ws, size_t ws_size,
                              hipStream_t stream)
{
  const float* x       = (const float*)d_in[0];
  const float* tok_w   = (const float*)d_in[1];
  const float* tok_b   = (const float*)d_in[2];
  const float* cat_emb = (const float*)d_in[3];
  const float* Wqkv    = (const float*)d_in[4];
  const float* bqkv    = (const float*)d_in[5];
  const float* Wout    = (const float*)d_in[6];
  const float* bout    = (const float*)d_in[7];
  const float* W0      = (const float*)d_in[8];
  const float* b0      = (const float*)d_in[9];
  const float* W1      = (const float*)d_in[10];
  const float* b1      = (const float*)d_in[11];
  const float* ln0_g   = (const float*)d_in[12];
  const float* ln0_b   = (const float*)d_in[13];
  const float* ln1_g   = (const float*)d_in[14];
  const float* ln1_b   = (const float*)d_in[15];

  size_t off = 0;
  char* base = (char*)d_ws;
  auto alloc = [&](size_t n) { char* p = base + off; off += (n + 255) & ~(size_t)255; return p; };
  float*  h     = (float*) alloc((size_t)M_ROWS * 512 * 4);
  bf16_t* ab    = (bf16_t*)alloc((size_t)M_ROWS * 512 * 2);   // LN out, frag KT=16
  bf16_t* qkv   = (bf16_t*)alloc((size_t)M_ROWS * 1536 * 2);  // frag KT=48
  bf16_t* attno = (bf16_t*)alloc((size_t)M_ROWS * 512 * 2);   // frag KT=16
  bf16_t* regl  = (bf16_t*)alloc((size_t)M_ROWS * 704 * 2);   // frag KT=22
  bf16_t* WqkvT = (bf16_t*)alloc((size_t)6 * 1536 * 512 * 2);
  bf16_t* WoutT = (bf16_t*)alloc((size_t)6 * 512 * 512 * 2);
  bf16_t* W0T   = (bf16_t*)alloc((size_t)6 * 1408 * 512 * 2);  // pair-interleaved
  bf16_t* W1T   = (bf16_t*)alloc((size_t)6 * 512 * 704 * 2);
  (void)ws_size; (void)in_sizes; (void)n_in; (void)out_size;

  dim3 tb(32, 8, 1);
  transpose_cvt<0><<<dim3(16, 48, 6), tb, 0, stream>>>(Wqkv, WqkvT, 512, 1536, 512, 1536);
  transpose_cvt<0><<<dim3(16, 16, 6), tb, 0, stream>>>(Wout, WoutT, 512, 512, 512, 512);
  transpose_cvt<1><<<dim3(16, 44, 6), tb, 0, stream>>>(W0, W0T, 512, 1364, 512, 1408);
  transpose_cvt<0><<<dim3(22, 16, 6), tb, 0, stream>>>(W1, W1T, 682, 512, 704, 512);

  tokenizer_kernel<<<M_ROWS / 4, 256, 0, stream>>>(x, tok_w, tok_b, cat_emb, h, ab);

  for (int i = 0; i < 6; i++) {
    if (i)
      ln_kernel<<<M_ROWS / 4, 256, 0, stream>>>(h, ab, ln0_g + (size_t)i * 512,
                                                ln0_b + (size_t)i * 512);
    gemm_frag<0><<<dim3(12, 129), 256, 0, stream>>>(
        ab, WqkvT + (size_t)i * 1536 * 512, bqkv + (size_t)i * 1536, 1536, nullptr, qkv, 512, 1536);
    attn_kernel<<<1024, 256, 0, stream>>>(qkv, attno);
    gemm_frag<1><<<dim3(4, 129), 256, 0, stream>>>(
        attno, WoutT + (size_t)i * 512 * 512, bout + (size_t)i * 512, 512, h, h, 512, 512);
    ln_kernel<<<M_ROWS / 4, 256, 0, stream>>>(h, ab, ln1_g + (size_t)i * 512,
                                              ln1_b + (size_t)i * 512);
    gemm_frag<2><<<dim3(11, 129), 256, 0, stream>>>(
        ab, W0T + (size_t)i * 1408 * 512, b0 + (size_t)i * 1364, 1364, nullptr, regl, 512, 1408);
    gemm_frag<1><<<dim3(4, 129), 256, 0, stream>>>(
        regl, W1T + (size_t)i * 512 * 704, b1 + (size_t)i * 512, 512, h, h, 704, 512);
  }

  out_copy<<<128, 256, 0, stream>>>(h, (float*)d_out);
}